// Round 5
// baseline (10.262 us; speedup 1.0000x reference)
//
#include <hip/hip_runtime.h>
#include <hip/hip_bf16.h>
#include <math.h>

#define T_STEPS 1024
#define BATCH_N 256
#define HID 8
#define N_ROWS 1026    // 1024 outs rows + hx + cx; each row = 2048 floats
#define GRID_B 256     // one block per CU; 16 waves/block
#define BLOCK_T 1024

// Native single-instruction transcendentals (accuracy ~1e-6, threshold 7e-3).
// v_sin/v_cos take REVOLUTIONS; v_exp/v_log are exp2/log2.
__device__ __forceinline__ float fexp2(float x) { return __builtin_amdgcn_exp2f(x); }
__device__ __forceinline__ float flog2(float x) { return __builtin_amdgcn_logf(x); }
__device__ __forceinline__ float frcp (float x) { return __builtin_amdgcn_rcpf(x); }
#define RCP_2PI 0.15915494309189535f
#define LOG2E   1.4426950408889634f
__device__ __forceinline__ float fsin(float rad) { return __builtin_amdgcn_sinf(rad * RCP_2PI); }
__device__ __forceinline__ float fcos(float rad) { return __builtin_amdgcn_cosf(rad * RCP_2PI); }
__device__ __forceinline__ float fsigmoid(float x) { return frcp(1.0f + fexp2(-LOG2E * x)); }
__device__ __forceinline__ float ftanh(float x) {
  return 1.0f - 2.0f * frcp(fexp2(2.0f * LOG2E * x) + 1.0f);
}

// Fused kernel, 256 blocks x 1024 threads (16 waves).
//
// Phase 1 (sim, waves 0-3 only): wave w computes <Z_q7> for param set w of
// the 8-qubit, 2-layer Ry+CNOT-ladder circuit. 256 real amplitudes, 4/lane:
// slot x = (r<<6)|lane, qubit q <-> flat bit (7-q).
//
// CNOT ladders are GF(2)-linear basis permutations Λ, FOLDED OUT:
//  - layer-1 Ry on |0..0> is a product state, kept in slot coords;
//  - layer-2 Ry on bit b pairs slot x with x ^ Λ^{-1}(1<<b), role bit
//    = bit_b(Λ(x));
//  - ladder 2 + measurement fold to sign(x) = (-1)^parity(Λ(x)).
// Λ = suffix-parity map: S = x^(x>>1); S^=S>>2; S^=S>>4;
//     Λ(x) = (S & 0x7F) | ((bit7(x) ^ (S&1)) << 7).
// Partner masks Λ^{-1}(1<<b), b=7..0: 0xC0,0x60,0x30,0x18,0x0C,0x06,0x03,0xC1.
//
// Phase 2 (write, all 16 waves): closed-form recurrence (block-uniform):
//   c_t = i*g*(1-f^(t+1))/(1-f),  a_t = o*tanh(c_t)
//   outs[t,b,h] = a_t*rowsum(Wp)[h] + bp[h]; row 1024 = hx, row 1025 = cx.
// Each 256-thread group writes one 2048-float row; 4 rows per block-iter.
__global__ __launch_bounds__(BLOCK_T) void qlstm_fused(
    const float* __restrict__ pf, const float* __restrict__ pi_,
    const float* __restrict__ pu, const float* __restrict__ po,
    const float* __restrict__ Wp, const float* __restrict__ bp,
    float* __restrict__ out) {
  const int tid = threadIdx.x;

  __shared__ float ev[4];
  __shared__ float swr[HID], sbr[HID];
  if (tid < HID) {
    float s = 0.0f;
    #pragma unroll
    for (int q = 0; q < 8; ++q) s += Wp[tid * 8 + q];
    swr[tid] = s;
    sbr[tid] = bp[tid];
  }

  if (tid < 256) {               // sim: waves 0-3, one circuit each
    const int lane = tid & 63;
    const int w    = tid >> 6;
    const float* p = (w == 0) ? pf : (w == 1) ? pi_ : (w == 2) ? pu : po;

    // half-angle sin/cos (wave-uniform values, native v_sin/v_cos)
    float sn[16], cs[16];
    #pragma unroll
    for (int k = 0; k < 16; ++k) {
      const float th = 0.5f * p[k];
      sn[k] = fsin(th);
      cs[k] = fcos(th);
    }

    // Lx[r] = Λ(slot), msign[r] = (-1)^parity(Λ(slot))
    int   Lx[4];
    float msign[4];
    #pragma unroll
    for (int r = 0; r < 4; ++r) {
      const int x = (r << 6) | lane;
      int S = x ^ (x >> 1); S ^= S >> 2; S ^= S >> 4;        // suffix parities
      Lx[r] = (S & 0x7F) | ((((x >> 7) ^ S) & 1) << 7);
      msign[r] = (__popc(Lx[r]) & 1) ? -1.0f : 1.0f;
    }

    // Layer-1 Ry product state: amp(x) = prod_b (bit_b(x) ? sn[7-b] : cs[7-b])
    float lp = 1.0f;
    #pragma unroll
    for (int b = 0; b < 6; ++b) lp *= ((lane >> b) & 1) ? sn[7 - b] : cs[7 - b];
    float amp[4];
    #pragma unroll
    for (int r = 0; r < 4; ++r)
      amp[r] = lp * ((r & 1) ? sn[1] : cs[1]) * ((r & 2) ? sn[0] : cs[0]);

    // Layer-2 Ry gates in folded coordinates.
    float pv[4];
    // q=0: m'=0xC0 (register swap r^3), role bit7
    #pragma unroll
    for (int r = 0; r < 4; ++r) pv[r] = amp[r ^ 3];
    #pragma unroll
    for (int r = 0; r < 4; ++r)
      amp[r] = fmaf(cs[8], amp[r], (((Lx[r] >> 7) & 1) ? sn[8] : -sn[8]) * pv[r]);
    // q=1: m'=0x60 (r^1, lane^32), role bit6
    #pragma unroll
    for (int r = 0; r < 4; ++r) pv[r] = __shfl_xor(amp[r ^ 1], 32, 64);
    #pragma unroll
    for (int r = 0; r < 4; ++r)
      amp[r] = fmaf(cs[9], amp[r], (((Lx[r] >> 6) & 1) ? sn[9] : -sn[9]) * pv[r]);
    // q=2..6: lane masks 0x30,0x18,0x0C,0x06,0x03; role bits 5..1
    #pragma unroll
    for (int q = 2; q <= 6; ++q) {
      const int b = 7 - q;
      const int m = (3 << (b - 1)) & 63;
      #pragma unroll
      for (int r = 0; r < 4; ++r) pv[r] = __shfl_xor(amp[r], m, 64);
      #pragma unroll
      for (int r = 0; r < 4; ++r)
        amp[r] = fmaf(cs[8 + q], amp[r],
                      (((Lx[r] >> b) & 1) ? sn[8 + q] : -sn[8 + q]) * pv[r]);
    }
    // q=7: m'=0xC1 (r^3, lane^1), role bit0
    #pragma unroll
    for (int r = 0; r < 4; ++r) pv[r] = __shfl_xor(amp[r ^ 3], 1, 64);
    #pragma unroll
    for (int r = 0; r < 4; ++r)
      amp[r] = fmaf(cs[15], amp[r], ((Lx[r] & 1) ? sn[15] : -sn[15]) * pv[r]);

    // <Z_q7> = sum msign * amp^2, wave butterfly reduce
    float v = msign[0] * amp[0] * amp[0] + msign[1] * amp[1] * amp[1] +
              msign[2] * amp[2] * amp[2] + msign[3] * amp[3] * amp[3];
    #pragma unroll
    for (int off = 1; off < 64; off <<= 1) v += __shfl_xor(v, off, 64);
    if (lane == 0) ev[w] = v;
  }
  __syncthreads();

  // Gate scalars (block-uniform). f = sigmoid in (0.269,0.731).
  const float f   = fsigmoid(ev[0]);
  const float ii  = fsigmoid(ev[1]);
  const float g   = ftanh(ev[2]);
  const float o   = fsigmoid(ev[3]);
  const float inv = ii * g * frcp(1.0f - f);
  const float lf2 = flog2(f);                 // f^n = exp2(n*log2(f))

  const int sub = tid >> 8;    // 0..3: row-group within an iteration
  const int col = tid & 255;   // position within the 2048-float row
  for (int row = blockIdx.x * 4 + sub; row < N_ROWS; row += GRID_B * 4) {
    float vals[8];
    if (row <= T_STEPS) {
      const int t = (row < T_STEPS) ? row : (T_STEPS - 1);   // hx = a_{T-1} row
      const float c  = inv * (1.0f - fexp2((float)(t + 1) * lf2));
      const float at = o * ftanh(c);
      #pragma unroll
      for (int h = 0; h < HID; ++h) vals[h] = fmaf(at, swr[h], sbr[h]);
    } else {
      const float cT = inv * (1.0f - fexp2((float)T_STEPS * lf2));
      #pragma unroll
      for (int h = 0; h < HID; ++h) vals[h] = cT;
    }
    float* dst = out + (size_t)row * 2048 + col * 8;
    *reinterpret_cast<float4*>(dst)     = make_float4(vals[0], vals[1], vals[2], vals[3]);
    *reinterpret_cast<float4*>(dst + 4) = make_float4(vals[4], vals[5], vals[6], vals[7]);
  }
}

extern "C" void kernel_launch(void* const* d_in, const int* in_sizes, int n_in,
                              void* d_out, int out_size, void* d_ws, size_t ws_size,
                              hipStream_t stream) {
  // setup_inputs order:
  // 0 inputs, 1 Wf, 2 bf, 3 Wi, 4 bi, 5 Wu, 6 bu, 7 Wo, 8 bo,
  // 9 pf, 10 pi, 11 pu, 12 po, 13 Wp, 14 bp
  const float* pf  = (const float*)d_in[9];
  const float* pi_ = (const float*)d_in[10];
  const float* pu  = (const float*)d_in[11];
  const float* po  = (const float*)d_in[12];
  const float* Wp  = (const float*)d_in[13];
  const float* bp  = (const float*)d_in[14];
  float* out = (float*)d_out;

  qlstm_fused<<<GRID_B, BLOCK_T, 0, stream>>>(pf, pi_, pu, po, Wp, bp, out);
}